// Round 8
// baseline (1401.815 us; speedup 1.0000x reference)
//
#include <hip/hip_runtime.h>
#include <math.h>

// Problem constants
#define NTOT 32768   // T*B
#define CIN  201
#define S    67      // keypoints (seq len)
#define E    8
#define H    2
#define L    12
#define FF   16
#define OUTC 128
#define KF   536     // S*E
#define EPB  7       // elements per block
#define LPE  34      // lanes per element; lane j owns rows 2j, 2j+1 (row 67 = pad)
#define THREADS 256  // 7*34 = 238 active (93%)
#define NPAIR 34     // t-pair slots; slot 33 = {t=66 real, t=67 zero-pad}

typedef float v2f __attribute__((ext_vector_type(2)));
typedef _Float16 v2h __attribute__((ext_vector_type(2)));
typedef __fp16   v2hf __attribute__((ext_vector_type(2)));

#if __has_builtin(__builtin_amdgcn_exp2f)
#define EXP2F(x) __builtin_amdgcn_exp2f(x)
#else
#define EXP2F(x) exp2f(x)
#endif
#if __has_builtin(__builtin_amdgcn_rcpf)
#define RCPF(x) __builtin_amdgcn_rcpf(x)
#else
#define RCPF(x) (1.0f/(x))
#endif
#if __has_builtin(__builtin_amdgcn_rsqf)
#define RSQF(x) __builtin_amdgcn_rsqf(x)
#else
#define RSQF(x) rsqrtf(x)
#endif
// v_dot2_f32_f16: 2 f16 MACs, f32 accumulate, full rate (2x fp32 FLOP density)
#if __has_builtin(__builtin_amdgcn_fdot2)
#define FDOT2(a,b,c) __builtin_amdgcn_fdot2((a),(b),(c),false)
#else
#define FDOT2(a,b,c) ((float)(a).x*(float)(b).x + (float)(a).y*(float)(b).y + (c))
#endif

// f32 pair -> f16x2 (RTZ); bit-cast __fp16x2 -> _Float16x2 for fdot2
static __device__ __forceinline__ v2h CVTPK(float a, float b) {
#if __has_builtin(__builtin_amdgcn_cvt_pkrtz)
    union { v2hf f; v2h h; } x;
    x.f = __builtin_amdgcn_cvt_pkrtz(a, b);
    return x.h;
#else
    return (v2h){(_Float16)a, (_Float16)b};
#endif
}

// 0.5 (=1/sqrt(DH)) * log2(e)
#define QSCALE 0.7213475204444817f

__device__ __forceinline__ v2f sp(float x) { return (v2f){x, x}; }
__device__ __forceinline__ unsigned int h2u(v2h h){ union{v2h h;unsigned int u;}x; x.h=h; return x.u; }
__device__ __forceinline__ v2h u2h(unsigned int u){ union{unsigned int u;v2h h;}x; x.u=u; return x.h; }

__device__ __forceinline__ void ln8p(v2f* x, const float* __restrict__ gg,
                                     const float* __restrict__ bb) {
    v2f m = {0.f, 0.f};
    #pragma unroll
    for (int e = 0; e < E; ++e) m += x[e];
    m *= 0.125f;
    v2f v = {0.f, 0.f};
    #pragma unroll
    for (int e = 0; e < E; ++e) { v2f d = x[e] - m; v += d * d; }
    v *= 0.125f;
    v2f rs;
    rs.x = RSQF(v.x + 1e-5f);
    rs.y = RSQF(v.y + 1e-5f);
    #pragma unroll
    for (int e = 0; e < E; ++e) x[e] = (x[e] - m) * rs * sp(gg[e]) + sp(bb[e]);
}

// Pack f16x2 weight pairs per layer into wph[L][256] (uint):
//  [0:96)   qkv: j*4+p  = {ipw[l][j][2p], ipw[l][j][2p+1]}   j<24
//  [96:128) aow: e*4+p  = {aow[l][e][2p], [2p+1]}
//  [128:192) f1: f*4+p  = {f1w[l][f][2p], [2p+1]}            f<16
//  [192:256) f2: e*8+p  = {f2w[l][e][2p], [2p+1]}            p<8
__global__ void prep_kernel(const float* __restrict__ ipw, const float* __restrict__ aow,
                            const float* __restrict__ f1w, const float* __restrict__ f2w,
                            unsigned int* __restrict__ wph)
{
    int idx = blockIdx.x * 256 + threadIdx.x;
    if (idx >= L * 256) return;
    int l = idx >> 8, r = idx & 255;
    float a, b;
    if (r < 96)       { int j = r >> 2, p = r & 3; a = ipw[l*192 + j*8 + 2*p]; b = ipw[l*192 + j*8 + 2*p+1]; }
    else if (r < 128) { int q = r - 96;  int e = q >> 2, p = q & 3; a = aow[l*64 + e*8 + 2*p]; b = aow[l*64 + e*8 + 2*p+1]; }
    else if (r < 192) { int q = r - 128; int f = q >> 2, p = q & 3; a = f1w[l*128 + f*8 + 2*p]; b = f1w[l*128 + f*8 + 2*p+1]; }
    else              { int q = r - 192; int e = q >> 3, p = q & 7; a = f2w[l*128 + e*16 + 2*p]; b = f2w[l*128 + e*16 + 2*p+1]; }
    wph[idx] = h2u(CVTPK(a, b));
}

__global__ __launch_bounds__(THREADS, 6)
void enc_kernel(const float* __restrict__ pose,
                const float* __restrict__ ew,  const float* __restrict__ ebias,
                const unsigned int* __restrict__ wph, const float* __restrict__ ipb,
                const float* __restrict__ aob,
                const float* __restrict__ f1b, const float* __restrict__ f2b,
                const float* __restrict__ g1,  const float* __restrict__ b1,
                const float* __restrict__ g2,  const float* __restrict__ b2,
                float* __restrict__ xf)
{
    // f16 K/V, t-pair packed:
    // KHs[gh][i] = { k_t0{d0,d1}, k_t0{d2,d3}, k_t1{d0,d1}, k_t1{d2,d3} }
    // VHs[gh][i] = { {v_t0_d, v_t1_d} for d=0..3 }
    // 2 * 14 * 34 * 16 B = 15232 B
    __shared__ uint4 KHs[EPB * H][NPAIR];
    __shared__ uint4 VHs[EPB * H][NPAIR];

    const int lid = threadIdx.x;
    const int g   = lid / LPE;          // element in block (0..6 valid)
    const int j   = lid - g * LPE;      // t-pair index (0..33)
    const int n   = blockIdx.x * EPB + g;
    const bool active = (g < EPB) && (n < NTOT);
    const bool pad = (j == LPE - 1);    // lane 33: row 67 doesn't exist
    const int r0 = 2 * j;

    const v2h one2 = {(_Float16)1.0f, (_Float16)1.0f};

    // ---- embed (rows r0, r0+1 packed as .x/.y) ----
    v2f xr[E];
    if (active) {
        const float* p0 = pose + (size_t)n * CIN + 3 * r0;
        const float* p1 = pad ? p0 : (p0 + 3);
        v2f c0 = {p0[0], p1[0]};
        v2f c1 = {p0[1], p1[1]};
        v2f c2 = {p0[2], p1[2]};
        #pragma unroll
        for (int e = 0; e < E; ++e)
            xr[e] = sp(ebias[e]) + c0 * sp(ew[e*3+0]) + c1 * sp(ew[e*3+1])
                                 + c2 * sp(ew[e*3+2]);
    }

    #pragma unroll 1
    for (int l = 0; l < L; ++l) {
        const unsigned int* WL = wph + l * 256;
        const v2h* qkvh = (const v2h*)WL;          // [24][4]
        const v2h* aowh = (const v2h*)(WL + 96);   // [8][4]
        const v2h* f1h  = (const v2h*)(WL + 128);  // [16][4]
        const v2h* f2h  = (const v2h*)(WL + 192);  // [8][8]
        const float* Bq = ipb + l * 24;

        v2h qh[H][2][2];   // [head][row][d01/d23] f16 q pairs (pre-scaled)
        if (active) {
            // x as f16 e-pairs per row
            v2h xh0[4], xh1[4];
            #pragma unroll
            for (int p = 0; p < 4; ++p) {
                xh0[p] = CVTPK(xr[2*p].x, xr[2*p+1].x);
                xh1[p] = CVTPK(xr[2*p].y, xr[2*p+1].y);
            }
            // q rows 0..7
            #pragma unroll
            for (int c = 0; c < 4; ++c) {
                float a0b = Bq[2*c], a1b = Bq[2*c+1];
                float q0a = a0b, q0b = a1b, q1a = a0b, q1b = a1b;
                #pragma unroll
                for (int p = 0; p < 4; ++p) {
                    q0a = FDOT2(xh0[p], qkvh[(2*c)*4 + p], q0a);
                    q0b = FDOT2(xh0[p], qkvh[(2*c+1)*4 + p], q0b);
                    q1a = FDOT2(xh1[p], qkvh[(2*c)*4 + p], q1a);
                    q1b = FDOT2(xh1[p], qkvh[(2*c+1)*4 + p], q1b);
                }
                const int h = c >> 1, d = (c & 1) ? 1 : 0;
                qh[h][0][d] = CVTPK(q0a * QSCALE, q0b * QSCALE);
                qh[h][1][d] = CVTPK(q1a * QSCALE, q1b * QSCALE);
            }
            // k, v per head: rows 8+4h.. / 16+4h..
            #pragma unroll
            for (int h = 0; h < H; ++h) {
                float k0[4], k1[4], v0[4], v1[4];
                #pragma unroll
                for (int d = 0; d < 4; ++d) {
                    const int jk = 8 + 4*h + d, jv = 16 + 4*h + d;
                    float ak0 = Bq[jk], ak1 = Bq[jk];
                    float av0 = Bq[jv], av1 = Bq[jv];
                    #pragma unroll
                    for (int p = 0; p < 4; ++p) {
                        ak0 = FDOT2(xh0[p], qkvh[jk*4 + p], ak0);
                        ak1 = FDOT2(xh1[p], qkvh[jk*4 + p], ak1);
                        av0 = FDOT2(xh0[p], qkvh[jv*4 + p], av0);
                        av1 = FDOT2(xh1[p], qkvh[jv*4 + p], av1);
                    }
                    k0[d] = ak0; k1[d] = ak1; v0[d] = av0; v1[d] = av1;
                }
                if (pad) {   // t=67: k=0 (exp2(0)=1, fixed by lsum-1), v=0
                    #pragma unroll
                    for (int d = 0; d < 4; ++d) { k1[d] = 0.f; v1[d] = 0.f; }
                }
                const int gh = g*2 + h;
                KHs[gh][j] = make_uint4(h2u(CVTPK(k0[0], k0[1])), h2u(CVTPK(k0[2], k0[3])),
                                        h2u(CVTPK(k1[0], k1[1])), h2u(CVTPK(k1[2], k1[3])));
                VHs[gh][j] = make_uint4(h2u(CVTPK(v0[0], v1[0])), h2u(CVTPK(v0[1], v1[1])),
                                        h2u(CVTPK(v0[2], v1[2])), h2u(CVTPK(v0[3], v1[3])));
            }
        }
        __syncthreads();

        if (active) {
            float on0[E], on1[E];   // attention outputs per row
            #pragma unroll
            for (int h = 0; h < H; ++h) {
                const int gh = g*2 + h;
                const uint4* pK = KHs[gh];
                const uint4* pV = VHs[gh];
                const v2h qA0 = qh[h][0][0], qB0 = qh[h][0][1];
                const v2h qA1 = qh[h][1][0], qB1 = qh[h][1][1];
                float ls0 = 0.f, ls1 = 0.f;
                float o00=0.f,o01=0.f,o02=0.f,o03=0.f;
                float o10=0.f,o11=0.f,o12=0.f,o13=0.f;
                #pragma unroll
                for (int i = 0; i < NPAIR; ++i) {   // t = 0..67 (67 = zero-pad)
                    uint4 kk = pK[i];
                    uint4 vv = pV[i];
                    float s00 = FDOT2(qA0, u2h(kk.x), FDOT2(qB0, u2h(kk.y), 0.f));
                    float s01 = FDOT2(qA0, u2h(kk.z), FDOT2(qB0, u2h(kk.w), 0.f));
                    float s10 = FDOT2(qA1, u2h(kk.x), FDOT2(qB1, u2h(kk.y), 0.f));
                    float s11 = FDOT2(qA1, u2h(kk.z), FDOT2(qB1, u2h(kk.w), 0.f));
                    float e00 = EXP2F(s00), e01 = EXP2F(s01);
                    float e10 = EXP2F(s10), e11 = EXP2F(s11);
                    v2h ep0 = CVTPK(e00, e01);
                    v2h ep1 = CVTPK(e10, e11);
                    ls0 = FDOT2(ep0, one2, ls0);
                    ls1 = FDOT2(ep1, one2, ls1);
                    o00 = FDOT2(ep0, u2h(vv.x), o00);
                    o01 = FDOT2(ep0, u2h(vv.y), o01);
                    o02 = FDOT2(ep0, u2h(vv.z), o02);
                    o03 = FDOT2(ep0, u2h(vv.w), o03);
                    o10 = FDOT2(ep1, u2h(vv.x), o10);
                    o11 = FDOT2(ep1, u2h(vv.y), o11);
                    o12 = FDOT2(ep1, u2h(vv.z), o12);
                    o13 = FDOT2(ep1, u2h(vv.w), o13);
                }
                float i0 = RCPF(ls0 - 1.0f);   // remove pad's exp2(0)=1
                float i1 = RCPF(ls1 - 1.0f);
                on0[4*h+0] = o00*i0; on0[4*h+1] = o01*i0;
                on0[4*h+2] = o02*i0; on0[4*h+3] = o03*i0;
                on1[4*h+0] = o10*i1; on1[4*h+1] = o11*i1;
                on1[4*h+2] = o12*i1; on1[4*h+3] = o13*i1;
            }

            // attn_out + residual + LN1 (dot2 over e-pairs)
            {
                const float* BA = aob + l*E;
                v2h oh0[4], oh1[4];
                #pragma unroll
                for (int p = 0; p < 4; ++p) {
                    oh0[p] = CVTPK(on0[2*p], on0[2*p+1]);
                    oh1[p] = CVTPK(on1[2*p], on1[2*p+1]);
                }
                #pragma unroll
                for (int e = 0; e < E; ++e) {
                    float a0 = BA[e], a1 = BA[e];
                    #pragma unroll
                    for (int p = 0; p < 4; ++p) {
                        a0 = FDOT2(oh0[p], aowh[e*4 + p], a0);
                        a1 = FDOT2(oh1[p], aowh[e*4 + p], a1);
                    }
                    xr[e] += (v2f){a0, a1};
                }
            }
            ln8p(xr, g1 + l*E, b1 + l*E);

            // FF (dot2)
            {
                const float* B1 = f1b + l*FF;
                const float* B2 = f2b + l*E;
                v2h xh0[4], xh1[4];
                #pragma unroll
                for (int p = 0; p < 4; ++p) {
                    xh0[p] = CVTPK(xr[2*p].x, xr[2*p+1].x);
                    xh1[p] = CVTPK(xr[2*p].y, xr[2*p+1].y);
                }
                float t0[FF], t1v[FF];
                #pragma unroll
                for (int f = 0; f < FF; ++f) {
                    float a0 = B1[f], a1 = B1[f];
                    #pragma unroll
                    for (int p = 0; p < 4; ++p) {
                        a0 = FDOT2(xh0[p], f1h[f*4 + p], a0);
                        a1 = FDOT2(xh1[p], f1h[f*4 + p], a1);
                    }
                    t0[f] = fmaxf(a0, 0.f);
                    t1v[f] = fmaxf(a1, 0.f);
                }
                v2h th0[8], th1[8];
                #pragma unroll
                for (int p = 0; p < 8; ++p) {
                    th0[p] = CVTPK(t0[2*p], t0[2*p+1]);
                    th1[p] = CVTPK(t1v[2*p], t1v[2*p+1]);
                }
                #pragma unroll
                for (int e = 0; e < E; ++e) {
                    float a0 = B2[e], a1 = B2[e];
                    #pragma unroll
                    for (int p = 0; p < 8; ++p) {
                        a0 = FDOT2(th0[p], f2h[e*8 + p], a0);
                        a1 = FDOT2(th1[p], f2h[e*8 + p], a1);
                    }
                    xr[e] += (v2f){a0, a1};
                }
            }
            ln8p(xr, g2 + l*E, b2 + l*E);
        }
        __syncthreads();   // protect K/V before next layer overwrites
    }

    if (active) {
        float* dst = xf + (size_t)n * KF + r0 * E;
        *(float4*)(dst + 0) = make_float4(xr[0].x, xr[1].x, xr[2].x, xr[3].x);
        *(float4*)(dst + 4) = make_float4(xr[4].x, xr[5].x, xr[6].x, xr[7].x);
        if (!pad) {
            *(float4*)(dst + 8)  = make_float4(xr[0].y, xr[1].y, xr[2].y, xr[3].y);
            *(float4*)(dst + 12) = make_float4(xr[4].y, xr[5].y, xr[6].y, xr[7].y);
        }
    }
}

// wt[k][c] = ow[c][k]
__global__ void tr_kernel(const float* __restrict__ ow, float* __restrict__ wt)
{
    int i = blockIdx.x * 256 + threadIdx.x;
    if (i < OUTC * KF) {
        int c = i / KF, k = i - c * KF;
        wt[k * OUTC + c] = ow[i];
    }
}

// out = tanh(Xf[32768,536] @ Wt[536,128] + b)
__global__ __launch_bounds__(256, 4)
void out_kernel(const float* __restrict__ xf, const float* __restrict__ wt,
                const float* __restrict__ ob, float* __restrict__ out)
{
    __shared__ float Xs[32][68];
    const int lid = threadIdx.x;
    const int tx  = lid & 31;
    const int ty  = lid >> 5;
    const int n0  = blockIdx.x * 32;

    float acc[4][4] = {};

    #pragma unroll 1
    for (int kc = 0; kc < 9; ++kc) {
        const int kb = kc * 64;
        const int kw = (kc < 8) ? 64 : 24;
        __syncthreads();
        const int nvec = 32 * (kw >> 2);
        for (int i = lid; i < nvec; i += 256) {
            int r = i / (kw >> 2), kq = i - r * (kw >> 2);
            *(float4*)&Xs[r][kq*4] =
                *(const float4*)&xf[(size_t)(n0 + r) * KF + kb + kq*4];
        }
        __syncthreads();
        #pragma unroll 4
        for (int k = 0; k < kw; ++k) {
            float4 w4 = *(const float4*)&wt[(size_t)(kb + k) * OUTC + tx*4];
            #pragma unroll
            for (int i = 0; i < 4; ++i) {
                float x = Xs[ty*4 + i][k];
                acc[i][0] += x*w4.x; acc[i][1] += x*w4.y;
                acc[i][2] += x*w4.z; acc[i][3] += x*w4.w;
            }
        }
    }

    const float4 bb = *(const float4*)&ob[tx*4];
    #pragma unroll
    for (int i = 0; i < 4; ++i) {
        int r = n0 + ty*4 + i;
        float4 v;
        v.x = tanhf(acc[i][0] + bb.x);
        v.y = tanhf(acc[i][1] + bb.y);
        v.z = tanhf(acc[i][2] + bb.z);
        v.w = tanhf(acc[i][3] + bb.w);
        *(float4*)(out + (size_t)r * OUTC + tx*4) = v;
    }
}

extern "C" void kernel_launch(void* const* d_in, const int* in_sizes, int n_in,
                              void* d_out, int out_size, void* d_ws, size_t ws_size,
                              hipStream_t stream) {
    (void)in_sizes; (void)n_in; (void)out_size; (void)ws_size;
    const float* pose = (const float*)d_in[0];
    const float* ew   = (const float*)d_in[1];
    const float* eb   = (const float*)d_in[2];
    const float* ipw  = (const float*)d_in[3];
    const float* ipb  = (const float*)d_in[4];
    const float* aow  = (const float*)d_in[5];
    const float* aob  = (const float*)d_in[6];
    const float* f1w  = (const float*)d_in[7];
    const float* f1b  = (const float*)d_in[8];
    const float* f2w  = (const float*)d_in[9];
    const float* f2b  = (const float*)d_in[10];
    const float* g1   = (const float*)d_in[11];
    const float* b1   = (const float*)d_in[12];
    const float* g2   = (const float*)d_in[13];
    const float* b2   = (const float*)d_in[14];
    const float* ow   = (const float*)d_in[15];
    const float* ob   = (const float*)d_in[16];

    float* xf = (float*)d_ws;                               // 70.25 MB
    float* wt = xf + (size_t)NTOT * KF;                     // 268 KB
    unsigned int* wph = (unsigned int*)(wt + (size_t)KF * OUTC);  // 12 KB

    prep_kernel<<<(L*256 + 255)/256, 256, 0, stream>>>(ipw, aow, f1w, f2w, wph);
    const int grid1 = (NTOT + EPB - 1) / EPB;               // 4682
    enc_kernel<<<grid1, THREADS, 0, stream>>>(pose, ew, eb, wph, ipb, aob,
                                              f1b, f2b, g1, b1, g2, b2, xf);
    tr_kernel<<<(OUTC*KF + 255)/256, 256, 0, stream>>>(ow, wt);
    out_kernel<<<NTOT / 32, 256, 0, stream>>>(xf, wt, ob, (float*)d_out);
}